// Round 3
// baseline (422.141 us; speedup 1.0000x reference)
//
#include <hip/hip_runtime.h>
#include <math.h>

#define H 256
#define W 256
#define NB 8
#define CIN 64
#define COUT 128
#define HW (H * W)

typedef float f4v __attribute__((ext_vector_type(4)));

// ---------------------------------------------------------------------------
// Kernel A (fused): offset conv (k=0..2, all 64 ci) + tanh + cumsum -> ynew,
// plus kpmat folded in at blockIdx.z == NB.
// LDS-free, barrier-free offset conv: each lane loads its own aligned float4
// per tap row (3 rows); horizontal halo (j-1 / j+4) via __shfl from lane+-1,
// edge lanes (q==0 / q==7) override with a masked scalar load. Vertical 3x
// re-read is served by L1 (per-wave channel working set ~1.3 KB).
// 2-deep register prefetch with NAMED register sets (no runtime indexing).
// ---------------------------------------------------------------------------
__global__ __launch_bounds__(256) void kfused(const float* __restrict__ x,
                                              const float* __restrict__ offw,
                                              const float* __restrict__ convw,
                                              float* __restrict__ ynew,
                                              float* __restrict__ P) {
    if (blockIdx.z == NB) {
        // ---- kpmat: P[n][co][t], t = r*4+y (padded stride 16) ----
        __shared__ float xl[CIN * 4];
        __shared__ float wl[16 * 192];
        const int n = blockIdx.y;
        const int co0 = blockIdx.x * 16;
        const int tid = threadIdx.x;
        {
            int ci = tid >> 2, y = tid & 3;
            xl[tid] = x[(((size_t)n * CIN + ci) * H + y) * W];
        }
        for (int p = tid; p < 16 * 192; p += 256) wl[p] = convw[co0 * 192 + p];
        __syncthreads();
        if (tid < 192) {
            int co = tid / 12, t = tid - co * 12;
            int r = t >> 2, y = t & 3;
            float s = 0.f;
#pragma unroll
            for (int ci = 0; ci < CIN; ++ci) s += wl[co * 192 + ci * 3 + r] * xl[ci * 4 + y];
            P[((size_t)n * COUT + co0 + co) * 16 + t] = s;
        }
        return;
    }

    // ---- offset conv ----
    const int n = blockIdx.z;
    const int i0 = blockIdx.y * 32;
    const int j0 = blockIdx.x * 32;
    const int tid = threadIdx.x;
    const int wv = tid >> 6;
    const int lane = tid & 63;
    const int rloc = lane >> 3;       // 0..7 output row within wave
    const int q = lane & 7;           // col quad
    const int orow = i0 + 8 * wv + rloc;  // global output row (always valid)
    const int jq = j0 + q * 4;
    const int lprev = (lane - 1) & 63;  // in-range shfl sources
    const int lnext = (lane + 1) & 63;

    const bool isq0 = (q == 0), isq7 = (q == 7);
    const int ecol = isq0 ? (j0 - 1) : (j0 + 32);      // halo column for edge lanes
    const bool ecv = (isq0 | isq7) && ((unsigned)ecol < (unsigned)W);
    const int ecc = ecol < 0 ? 0 : (ecol > W - 1 ? W - 1 : ecol);  // safe addr

    const bool rv0 = (orow >= 1);
    const bool rv2 = (orow <= H - 2);
    const size_t ro0 = (size_t)(rv0 ? orow - 1 : 0) * W;
    const size_t ro1 = (size_t)orow * W;
    const size_t ro2 = (size_t)(rv2 ? orow + 1 : H - 1) * W;
    const bool ev0 = rv0 && ecv, ev1 = ecv, ev2 = rv2 && ecv;

    const float* xn = x + (size_t)n * CIN * HW;
    const float4 zf4 = make_float4(0.f, 0.f, 0.f, 0.f);

    float acc[3][4];
#pragma unroll
    for (int k = 0; k < 3; ++k)
#pragma unroll
        for (int d = 0; d < 4; ++d) acc[k][d] = 0.f;

#define LOADCH(c, M0, M1, M2, E0, E1, E2)                          \
    {                                                              \
        const float* xc = xn + (size_t)(c) * HW;                   \
        M0 = rv0 ? *(const float4*)(xc + ro0 + jq) : zf4;          \
        M1 = *(const float4*)(xc + ro1 + jq);                      \
        M2 = rv2 ? *(const float4*)(xc + ro2 + jq) : zf4;          \
        E0 = ev0 ? xc[ro0 + ecc] : 0.f;                            \
        E1 = ev1 ? xc[ro1 + ecc] : 0.f;                            \
        E2 = ev2 ? xc[ro2 + ecc] : 0.f;                            \
    }

#define CU(u, M, E)                                                \
    {                                                              \
        float lf = __shfl(M.w, lprev);                             \
        float rt = __shfl(M.x, lnext);                             \
        if (isq0) lf = E;                                          \
        if (isq7) rt = E;                                          \
        const float r0 = lf, r1 = M.x, r2 = M.y, r3 = M.z,         \
                    r4 = M.w, r5 = rt;                             \
        _Pragma("unroll") for (int k = 0; k < 3; ++k) {            \
            const float w0 = wp[k * 576 + (u)*3 + 0];              \
            const float w1 = wp[k * 576 + (u)*3 + 1];              \
            const float w2 = wp[k * 576 + (u)*3 + 2];              \
            acc[k][0] += r0 * w0 + r1 * w1 + r2 * w2;              \
            acc[k][1] += r1 * w0 + r2 * w1 + r3 * w2;              \
            acc[k][2] += r2 * w0 + r3 * w1 + r4 * w2;              \
            acc[k][3] += r3 * w0 + r4 * w1 + r5 * w2;              \
        }                                                          \
    }

#define COMPUTE(c, M0, M1, M2, E0, E1, E2)                         \
    {                                                              \
        const float* wp = offw + (size_t)(c) * 9;                  \
        CU(0, M0, E0) CU(1, M1, E1) CU(2, M2, E2)                  \
    }

    float4 Am0, Am1, Am2, Bm0, Bm1, Bm2;
    float Ae0, Ae1, Ae2, Be0, Be1, Be2;
    LOADCH(0, Am0, Am1, Am2, Ae0, Ae1, Ae2);
    LOADCH(1, Bm0, Bm1, Bm2, Be0, Be1, Be2);

    for (int c = 0; c < CIN; c += 2) {
        COMPUTE(c, Am0, Am1, Am2, Ae0, Ae1, Ae2);
        if (c + 2 < CIN) LOADCH(c + 2, Am0, Am1, Am2, Ae0, Ae1, Ae2);
        COMPUTE(c + 1, Bm0, Bm1, Bm2, Be0, Be1, Be2);
        if (c + 3 < CIN) LOADCH(c + 3, Bm0, Bm1, Bm2, Be0, Be1, Be2);
    }
#undef LOADCH
#undef CU
#undef COMPUTE

    // epilogue: tanh + cumsum combos, write ynew directly
    float y[3][4];
#pragma unroll
    for (int d = 0; d < 4; ++d) {
        float t0 = tanhf(acc[0][d]);
        float t1 = tanhf(acc[1][d]);
        float t2 = tanhf(acc[2][d]);
        y[0][d] = t0 + t1;
        y[1][d] = t1;
        y[2][d] = t1 + t2;
    }
    size_t base = (size_t)n * 3 * HW + (size_t)orow * W + jq;
#pragma unroll
    for (int k = 0; k < 3; ++k)
        *(float4*)(ynew + base + (size_t)k * HW) =
            make_float4(y[k][0], y[k][1], y[k][2], y[k][3]);
}

// ---------------------------------------------------------------------------
// Kernel C: out[n,co,i,j] = sum_t C[t](n,i,j) * P[n,co,t]  (unchanged, verified)
// ---------------------------------------------------------------------------
__global__ __launch_bounds__(256) void kout(const float* __restrict__ ynew,
                                            const float* __restrict__ P,
                                            float* __restrict__ out) {
    __shared__ float Cs[12 * 256];
    __shared__ float Pl[128 * 16];
    const int n = blockIdx.y;
    const int i = blockIdx.x;
    const int tid = threadIdx.x;

    {
        const f4v* src = (const f4v*)(P + (size_t)n * COUT * 16);
        f4v* dst = (f4v*)Pl;
        dst[tid] = src[tid];
        dst[tid + 256] = src[tid + 256];
    }

    {
        const int j = tid;
        float c[12];
#pragma unroll
        for (int t = 0; t < 12; ++t) c[t] = 0.f;
#pragma unroll
        for (int r = 0; r < 3; ++r) {
            int rowi = 3 * i + r;
            int k = rowi >> 8;
            int i2 = rowi & 255;
            float g = (float)(((k + i2 + j) % 3) - 1) +
                      ynew[((size_t)n * 3 + k) * (H * W) + i2 * W + j];
            float gy = g / 127.5f - 1.0f;
            float iy = ((gy + 1.0f) * 256.0f - 1.0f) * 0.5f;
            float fy = floorf(iy);
            int y0 = (int)fy;
            float w1 = iy - fy;
            if ((unsigned)y0 < 4u) c[r * 4 + y0] += 0.5f * (1.0f - w1);
            int y1 = y0 + 1;
            if ((unsigned)y1 < 4u) c[r * 4 + y1] += 0.5f * w1;
        }
#pragma unroll
        for (int t = 0; t < 12; ++t) Cs[t * 256 + j] = c[t];
    }
    __syncthreads();

    const int jq = (tid & 63) * 4;
    const int cg = tid >> 6;
    float4 cc[12];
#pragma unroll
    for (int t = 0; t < 12; ++t) cc[t] = *(const float4*)&Cs[t * 256 + jq];

    float* op = out + (((size_t)n * COUT) * H + i) * W;
    for (int co = cg * 32; co < cg * 32 + 32; ++co) {
        const float4* pp = (const float4*)&Pl[co * 16];
        float4 P0 = pp[0], P1 = pp[1], P2 = pp[2];
        float pv[12] = {P0.x, P0.y, P0.z, P0.w, P1.x, P1.y, P1.z, P1.w,
                        P2.x, P2.y, P2.z, P2.w};
        f4v a = {0.f, 0.f, 0.f, 0.f};
#pragma unroll
        for (int t = 0; t < 12; ++t) {
            a.x += pv[t] * cc[t].x;
            a.y += pv[t] * cc[t].y;
            a.z += pv[t] * cc[t].z;
            a.w += pv[t] * cc[t].w;
        }
        __builtin_nontemporal_store(a, (f4v*)(op + (size_t)co * (H * W) + jq));
    }
}

// ---------------------------------------------------------------------------
extern "C" void kernel_launch(void* const* d_in, const int* in_sizes, int n_in,
                              void* d_out, int out_size, void* d_ws, size_t ws_size,
                              hipStream_t stream) {
    const float* x = (const float*)d_in[0];      // [8,64,256,256]
    const float* offw = (const float*)d_in[1];   // [6,64,3,3]
    const float* convw = (const float*)d_in[2];  // [128,64,3,1]
    float* out = (float*)d_out;                  // [8,128,256,256]

    float* ynew = (float*)d_ws;                           // [8][3][256][256]
    float* P = ynew + (size_t)NB * 3 * HW;                // [8][128][16]

    kfused<<<dim3(8, 8, NB + 1), 256, 0, stream>>>(x, offw, convw, ynew, P);
    kout<<<dim3(H, NB), 256, 0, stream>>>(ynew, P, out);
}